// Round 6
// baseline (544.091 us; speedup 1.0000x reference)
//
#include <hip/hip_runtime.h>
#include <hip/hip_bf16.h>

typedef __attribute__((ext_vector_type(8))) short bf16x8;
typedef __attribute__((ext_vector_type(4))) float f32x4;

#define HID 512
#define NB 32
#define SEQL 4096
#define BM 32
#define NBLK 4096       // 131072 rows / 32

// workspace layout (bytes)
#define WS_BP    0              // packed bf16 W_enc: 512 KB
#define WS_DPROJ (512*1024)     // fp32 32x512: 64 KB
#define WS_SUM   (576*1024)     // fp32 32: 128 B

__device__ __forceinline__ short f2bf(float f) {
    unsigned u = __float_as_uint(f);
    unsigned r = (u + 0x7fffu + ((u >> 16) & 1u)) >> 16;   // RNE
    return (short)r;
}

__device__ __forceinline__ float fast_tanh(float x) {
    float e = __expf(2.0f * x);
    float r = __builtin_amdgcn_rcpf(e + 1.0f);
    return 1.0f - 2.0f * r;
}

// HW packed f32->bf16 RNE: one VOP3 per 2 floats (no builtin on gfx950 — asm)
__device__ __forceinline__ unsigned cvtpk(float lo, float hi) {
    unsigned r;
    asm("v_cvt_pk_bf16_f32 %0, %1, %2" : "=v"(r) : "v"(lo), "v"(hi));
    return r;
}
__device__ __forceinline__ bf16x8 pack8(const float4& A, const float4& B) {
    union { unsigned u[4]; bf16x8 v; } t;
    t.u[0] = cvtpk(A.x, A.y); t.u[1] = cvtpk(A.z, A.w);
    t.u[2] = cvtpk(B.x, B.y); t.u[3] = cvtpk(B.z, B.w);
    return t.v;
}

// ---------------------------------------------------------------------------
// K_pre (unchanged, R3/R7 measured): (a) W_enc pack fp32->bf16 B-frag layout
// [blk 0..127], (b) dproj GEMV 8-way h-parallel [blk 128..639],
// (c) zero ctx + sumacc [blk 640..703]
// ---------------------------------------------------------------------------
__global__ void k_pre(const float* __restrict__ We, short* __restrict__ Bp,
                      const float* __restrict__ dec, const float* __restrict__ Wd,
                      const float* __restrict__ be, const float* __restrict__ bd,
                      float* __restrict__ dproj, float* __restrict__ out,
                      float* __restrict__ sumacc) {
    const int blk = blockIdx.x, t = threadIdx.x;
    if (blk < 128) {
        // Bp[kc32][nt][lane][j] = We[kc32*32 + (lane>>4)*8 + j][nt*16 + (lane&15)]
        int tid  = blk * 256 + t;
        int lane = tid & 63;
        int nt   = (tid >> 6) & 31;
        int kc   = tid >> 11;
        int k0   = kc * 32 + (lane >> 4) * 8;
        int n    = nt * 16 + (lane & 15);
        bf16x8 v;
#pragma unroll
        for (int j = 0; j < 8; ++j) v[j] = f2bf(We[(size_t)(k0 + j) * HID + n]);
        *(bf16x8*)&Bp[(size_t)tid * 8] = v;
    } else if (blk < 640) {
        __shared__ float red[8][33];
        int bid2 = blk - 128;
        int b  = bid2 >> 4, kg = bid2 & 15;     // 32 batches x 16 k-groups
        int kl = t & 31,    hc = t >> 5;        // 32 k-cols x 8 h-chunks
        int k  = kg * 32 + kl;
        const float* dr = dec + (size_t)b * HID;
        float a = 0.f;
#pragma unroll 8
        for (int j = 0; j < 64; ++j) {
            int h = hc * 64 + j;
            a += dr[h] * Wd[(size_t)h * HID + k];
        }
        red[hc][kl] = a;
        __syncthreads();
        if (hc == 0) {
            float s = be[k] + bd[k];
#pragma unroll
            for (int c = 0; c < 8; ++c) s += red[c][kl];
            dproj[(size_t)b * HID + k] = s;
        }
    } else {
        int bz = blk - 640;
        out[bz * 256 + t] = 0.f;                // zero context region (16384 f32)
        if (bz == 0 && t < NB) sumacc[t] = 0.f;
    }
}

// ---------------------------------------------------------------------------
// K_main R10: barrier-free register-pipeline K-loop.
// - BM=32, wave tile 32x128: acc[2][8] = 64 regs -> launch_bounds(256,3)
//   targets 3 waves/SIMD (12 waves/CU) vs measured 2 (R8/R9 both 22% occ).
// - A fragments loaded DIRECTLY from global in MFMA fragment order (fully
//   line-coalesced: 64 lanes x 32 B contiguous each). 4-wave redundancy is
//   L1-absorbed (4 KB tile). No As LDS, no __syncthreads in the K-loop:
//   every wave is an independent pipeline. A prefetched 1 iter ahead (HBM
//   latency spans the full iteration).
// - fb from fragment-ordered Bp in L2 (R9 path), but K-chunk order STAGGERED
//   per block (kcs = (kc + bid&15)&15) to break the all-CUs-same-32KB-chunk
//   L2 channel hotspot that R8/R9 both suffered.
// - A convert via v_cvt_pk_bf16_f32 (8 instr/iter vs ~60 VALU bit-twiddle).
// ---------------------------------------------------------------------------
__global__ __launch_bounds__(256, 3)
void k_main(const float* __restrict__ E, const short* __restrict__ Bp,
            const float* __restrict__ dproj, const float* __restrict__ Wv,
            float* __restrict__ out, float* __restrict__ sumacc) {
    __shared__ float fbuf[512];
    __shared__ float pbuf[BM];

    const int tid  = threadIdx.x;
    const int wave = tid >> 6, lane = tid & 63;
    const int quad = lane >> 4, l15 = lane & 15;
    const int bid  = blockIdx.x;
    const int row0 = bid * BM;           // global row = b*4096 + s
    const int b    = bid >> 7;           // 128 blocks per batch
    const int stag = bid & 15;           // K-chunk stagger

    f32x4 acc[2][8];
#pragma unroll
    for (int r = 0; r < 2; ++r)
#pragma unroll
        for (int c = 0; c < 8; ++c) acc[r][c] = (f32x4){0.f, 0.f, 0.f, 0.f};

    // A fragment addresses: lane (quad,l15) holds A[row = r*16+l15][k = quad*8..+7]
    const float* a0p = E + (size_t)(row0 + l15) * HID + quad * 8;        // r=0
    const float* a1p = E + (size_t)(row0 + 16 + l15) * HID + quad * 8;   // r=1
    // B fragment base: Bp[kc][nt = wave*8 + c][lane][8 shorts]
    const short* bpw = Bp + ((size_t)(wave * 8) * 64 + lane) * 8;

    // prologue: A loads for first (staggered) chunk
    int kcs = stag;
    float4 a00 = *(const float4*)(a0p + kcs * 32);
    float4 a01 = *(const float4*)(a0p + kcs * 32 + 4);
    float4 a10 = *(const float4*)(a1p + kcs * 32);
    float4 a11 = *(const float4*)(a1p + kcs * 32 + 4);

    for (int kc = 0; kc < 16; ++kc) {
        // fb loads for current chunk (L2)
        const short* bsrc = bpw + (size_t)kcs * 16384;
        bf16x8 fb[8];
#pragma unroll
        for (int c = 0; c < 8; ++c)
            fb[c] = *(const bf16x8*)(bsrc + c * 512);
        // A prefetch for next chunk (HBM/L1) — consumed next iteration
        const int kn = (kcs + 1) & 15;
        float4 n00, n01, n10, n11;
        if (kc < 15) {
            n00 = *(const float4*)(a0p + kn * 32);
            n01 = *(const float4*)(a0p + kn * 32 + 4);
            n10 = *(const float4*)(a1p + kn * 32);
            n11 = *(const float4*)(a1p + kn * 32 + 4);
        }
        // convert current A (loaded last iter — latency already paid)
        bf16x8 fa0 = pack8(a00, a01);
        bf16x8 fa1 = pack8(a10, a11);
#pragma unroll
        for (int c = 0; c < 8; ++c) {
            acc[0][c] = __builtin_amdgcn_mfma_f32_16x16x32_bf16(fa0, fb[c], acc[0][c], 0, 0, 0);
            acc[1][c] = __builtin_amdgcn_mfma_f32_16x16x32_bf16(fa1, fb[c], acc[1][c], 0, 0, 0);
        }
        if (kc < 15) { a00 = n00; a01 = n01; a10 = n10; a11 = n11; }
        kcs = kn;
    }

    // ---- epilogue a: score = sum_col tanh(acc + dproj[col]) * Wv[col] ----
    // acc[r][c][g] = enc_proj[row0 + r*16 + quad*4 + g][wave*128 + c*16 + l15]
    float part[2][4];
#pragma unroll
    for (int r = 0; r < 2; ++r)
#pragma unroll
        for (int g = 0; g < 4; ++g) part[r][g] = 0.f;
    const float* dp = dproj + (size_t)b * HID;
#pragma unroll
    for (int c = 0; c < 8; ++c) {
        int col = wave * 128 + c * 16 + l15;
        float dv = dp[col];
        float wv = Wv[col];
#pragma unroll
        for (int r = 0; r < 2; ++r)
#pragma unroll
            for (int g = 0; g < 4; ++g)
                part[r][g] += fast_tanh(acc[r][c][g] + dv) * wv;
    }
    // reduce across the 16 col-lanes (bits 0..3 of lane)
#pragma unroll
    for (int r = 0; r < 2; ++r)
#pragma unroll
        for (int g = 0; g < 4; ++g) {
            float v = part[r][g];
            v += __shfl_xor(v, 1); v += __shfl_xor(v, 2);
            v += __shfl_xor(v, 4); v += __shfl_xor(v, 8);
            part[r][g] = v;
        }
    if (l15 == 0) {
#pragma unroll
        for (int r = 0; r < 2; ++r)
#pragma unroll
            for (int g = 0; g < 4; ++g)
                fbuf[wave * 32 + r * 16 + quad * 4 + g] = part[r][g];
    }
    __syncthreads();
    if (tid < 32) {
        float s  = fbuf[tid] + fbuf[32 + tid] + fbuf[64 + tid] + fbuf[96 + tid];
        float pv = __expf(s);           // unnormalized; b_v cancels in softmax
        pbuf[tid] = pv;
        out[(size_t)NB * HID + row0 + tid] = pv;   // weights region, normalized later
        float t2 = pv;
        t2 += __shfl_xor(t2, 1); t2 += __shfl_xor(t2, 2); t2 += __shfl_xor(t2, 4);
        t2 += __shfl_xor(t2, 8); t2 += __shfl_xor(t2, 16);
        if (tid == 0) atomicAdd(&sumacc[b], t2);
    }
    __syncthreads();

    // ---- epilogue b: partial context = sum_rows pv * E[row,:] (L1/L2-hot) ----
    const int hq = tid & 127, rh = tid >> 7;       // h = hq*4, rows rh*16..rh*16+15
    const float4* E4 = (const float4*)E;
    size_t cbase = (size_t)(row0 + rh * 16) * (HID / 4) + hq;
    float4 ca = {0.f, 0.f, 0.f, 0.f};
#pragma unroll 4
    for (int rr = 0; rr < 16; ++rr) {
        float w  = pbuf[rh * 16 + rr];
        float4 e = E4[cbase + (size_t)rr * (HID / 4)];
        ca.x += w * e.x; ca.y += w * e.y; ca.z += w * e.z; ca.w += w * e.w;
    }
    if (rh == 1) {
        fbuf[hq] = ca.x; fbuf[128 + hq] = ca.y; fbuf[256 + hq] = ca.z; fbuf[384 + hq] = ca.w;
    }
    __syncthreads();
    if (rh == 0) {
        ca.x += fbuf[hq]; ca.y += fbuf[128 + hq]; ca.z += fbuf[256 + hq]; ca.w += fbuf[384 + hq];
        float* cg = out + (size_t)b * HID + hq * 4;   // context region of d_out
        atomicAdd(cg + 0, ca.x); atomicAdd(cg + 1, ca.y);
        atomicAdd(cg + 2, ca.z); atomicAdd(cg + 3, ca.w);
    }
}

// ---------------------------------------------------------------------------
// K_finish: normalize in place, full-grid. 147456 floats / 256 = 576 blocks.
// ---------------------------------------------------------------------------
__global__ void k_finish(float* __restrict__ out, const float* __restrict__ sumacc) {
    int idx = blockIdx.x * 256 + threadIdx.x;
    if (idx < NB * HID) {
        out[idx] *= 1.0f / sumacc[idx >> 9];           // context: b = idx/HID
    } else {
        int w = idx - NB * HID;
        out[idx] *= 1.0f / sumacc[w >> 12];            // weights: b = w/SEQL
    }
}

extern "C" void kernel_launch(void* const* d_in, const int* in_sizes, int n_in,
                              void* d_out, int out_size, void* d_ws, size_t ws_size,
                              hipStream_t stream) {
    const float* E   = (const float*)d_in[0];
    const float* dec = (const float*)d_in[1];
    const float* We  = (const float*)d_in[2];
    const float* be  = (const float*)d_in[3];
    const float* Wd  = (const float*)d_in[4];
    const float* bd  = (const float*)d_in[5];
    const float* Wv  = (const float*)d_in[6];
    // d_in[7] = b_v: uniform shift per score -> cancels in softmax
    float* out = (float*)d_out;
    char*  ws  = (char*)d_ws;
    short* Bp     = (short*)(ws + WS_BP);
    float* dproj  = (float*)(ws + WS_DPROJ);
    float* sumacc = (float*)(ws + WS_SUM);

    k_pre<<<704, 256, 0, stream>>>(We, Bp, dec, Wd, be, bd, dproj, out, sumacc);
    k_main<<<NBLK, 256, 0, stream>>>(E, Bp, dproj, Wv, out, sumacc);
    k_finish<<<576, 256, 0, stream>>>(out, sumacc);
}

// Round 9
// 519.821 us; speedup vs baseline: 1.0467x; 1.0467x over previous
//
#include <hip/hip_runtime.h>
#include <hip/hip_bf16.h>

typedef __attribute__((ext_vector_type(8))) short bf16x8;
typedef __attribute__((ext_vector_type(4))) float f32x4;

#define HID 512
#define NB 32
#define SEQL 4096
#define BM 64
#define NBLK 2048       // 131072 rows / 64

// workspace layout (bytes)
#define WS_BP    0              // packed bf16 W_enc: 512 KB
#define WS_DPROJ (512*1024)     // fp32 32x512: 64 KB
#define WS_SUM   (576*1024)     // fp32 32: 128 B

__device__ __forceinline__ short f2bf(float f) {
    unsigned u = __float_as_uint(f);
    unsigned r = (u + 0x7fffu + ((u >> 16) & 1u)) >> 16;   // RNE
    return (short)r;
}

__device__ __forceinline__ float fast_tanh(float x) {
    float e = __expf(2.0f * x);
    float r = __builtin_amdgcn_rcpf(e + 1.0f);
    return 1.0f - 2.0f * r;
}

// HW packed f32->bf16 RNE (no builtin on gfx950 — inline asm)
__device__ __forceinline__ unsigned cvtpk(float lo, float hi) {
    unsigned r;
    asm("v_cvt_pk_bf16_f32 %0, %1, %2" : "=v"(r) : "v"(lo), "v"(hi));
    return r;
}
__device__ __forceinline__ bf16x8 pack8(const float4& A, const float4& B) {
    union { unsigned u[4]; bf16x8 v; } t;
    t.u[0] = cvtpk(A.x, A.y); t.u[1] = cvtpk(A.z, A.w);
    t.u[2] = cvtpk(B.x, B.y); t.u[3] = cvtpk(B.z, B.w);
    return t.v;
}

__device__ __forceinline__ void async16(const void* g, void* l) {
    __builtin_amdgcn_global_load_lds((__attribute__((address_space(1))) void*)(g),
                                     (__attribute__((address_space(3))) void*)(l),
                                     16, 0, 0);
}

// ---------------------------------------------------------------------------
// K_pre (unchanged, R3/R7 measured): (a) W_enc pack fp32->bf16 B-frag layout
// [blk 0..127], (b) dproj GEMV 8-way h-parallel [blk 128..639],
// (c) zero ctx + sumacc [blk 640..703]
// ---------------------------------------------------------------------------
__global__ void k_pre(const float* __restrict__ We, short* __restrict__ Bp,
                      const float* __restrict__ dec, const float* __restrict__ Wd,
                      const float* __restrict__ be, const float* __restrict__ bd,
                      float* __restrict__ dproj, float* __restrict__ out,
                      float* __restrict__ sumacc) {
    const int blk = blockIdx.x, t = threadIdx.x;
    if (blk < 128) {
        // Bp[kc32][nt][lane][j] = We[kc32*32 + (lane>>4)*8 + j][nt*16 + (lane&15)]
        int tid  = blk * 256 + t;
        int lane = tid & 63;
        int nt   = (tid >> 6) & 31;
        int kc   = tid >> 11;
        int k0   = kc * 32 + (lane >> 4) * 8;
        int n    = nt * 16 + (lane & 15);
        bf16x8 v;
#pragma unroll
        for (int j = 0; j < 8; ++j) v[j] = f2bf(We[(size_t)(k0 + j) * HID + n]);
        *(bf16x8*)&Bp[(size_t)tid * 8] = v;
    } else if (blk < 640) {
        __shared__ float red[8][33];
        int bid2 = blk - 128;
        int b  = bid2 >> 4, kg = bid2 & 15;     // 32 batches x 16 k-groups
        int kl = t & 31,    hc = t >> 5;        // 32 k-cols x 8 h-chunks
        int k  = kg * 32 + kl;
        const float* dr = dec + (size_t)b * HID;
        float a = 0.f;
#pragma unroll 8
        for (int j = 0; j < 64; ++j) {
            int h = hc * 64 + j;
            a += dr[h] * Wd[(size_t)h * HID + k];
        }
        red[hc][kl] = a;
        __syncthreads();
        if (hc == 0) {
            float s = be[k] + bd[k];
#pragma unroll
            for (int c = 0; c < 8; ++c) s += red[c][kl];
            dproj[(size_t)b * HID + k] = s;
        }
    } else {
        int bz = blk - 640;
        out[bz * 256 + t] = 0.f;                // zero context region (16384 f32)
        if (bz == 0 && t < NB) sumacc[t] = 0.f;
    }
}

// ---------------------------------------------------------------------------
// K_main R11: counted-vmcnt pipeline (T4). Serial-phase accounting of R8
// (MFMA 29 + B-L2 31 + A-HBM 41 + LDS 33 + VALU 37 us ~= measured 205) says
// subsystems run serially; hbm at 16% peak because __syncthreads' vmcnt(0)
// drains the A prefetch every iter (low duty cycle).
// - B: async16 -> Bs dbuf (R8's only measured-good path), BK=32, 16 iters.
// - A: direct fragment-order register loads (R10 component: 0 conflicts,
//   FETCH stable), prefetched 1 iter ahead. No As LDS at all.
// - Barrier: asm s_waitcnt vmcnt(8) + raw s_barrier. Issue order per iter is
//   8 asyncs THEN 8 A-floats4s, so vmcnt(8) at the next iter top drains
//   exactly the asyncs (buffer publish) while A loads STAY IN FLIGHT across
//   the barrier -> continuous HBM stream.
// - Per-block K-chunk stagger de-lockstops co-resident blocks (R10-shipped).
// ---------------------------------------------------------------------------
__global__ __launch_bounds__(256, 2)
void k_main(const float* __restrict__ E, const short* __restrict__ Bp,
            const float* __restrict__ dproj, const float* __restrict__ Wv,
            float* __restrict__ out, float* __restrict__ sumacc) {
    __shared__ short Bs[2][32 * HID];    // 2 x 32 KB
    __shared__ float fbuf[640];
    __shared__ float pbuf[BM];

    const int tid  = threadIdx.x;
    const int wave = tid >> 6, lane = tid & 63;
    const int quad = lane >> 4, l15 = lane & 15;
    const int bid  = blockIdx.x;
    const int row0 = bid * BM;           // global row = b*4096 + s
    const int b    = bid >> 6;           // 64 blocks per batch
    const int stag = bid & 15;           // K-chunk stagger

    f32x4 acc[4][8];
#pragma unroll
    for (int r = 0; r < 4; ++r)
#pragma unroll
        for (int c = 0; c < 8; ++c) acc[r][c] = (f32x4){0.f, 0.f, 0.f, 0.f};

    // A fragment base: lane (quad,l15), rowgroup r -> row r*16+l15, k=quad*8..+7
    const float* aE = E + (size_t)(row0 + l15) * HID + quad * 8;

    int kcs = stag;
    // ---- prologue: stage B(kcs) into Bs[0], load A(kcs) into regs ----
    {
        const short* bsrc = Bp + (size_t)kcs * 16384;
#pragma unroll
        for (int i = 0; i < 8; ++i) {
            int off = (i * 4 + wave) * 512;          // shorts; HW adds lane*16 B
            async16(bsrc + off + lane * 8, &Bs[0][off]);
        }
    }
    __builtin_amdgcn_sched_barrier(0);
    float4 c0a = *(const float4*)(aE + 0 * 8192 + kcs * 32);
    float4 c0b = *(const float4*)(aE + 0 * 8192 + kcs * 32 + 4);
    float4 c1a = *(const float4*)(aE + 1 * 8192 + kcs * 32);
    float4 c1b = *(const float4*)(aE + 1 * 8192 + kcs * 32 + 4);
    float4 c2a = *(const float4*)(aE + 2 * 8192 + kcs * 32);
    float4 c2b = *(const float4*)(aE + 2 * 8192 + kcs * 32 + 4);
    float4 c3a = *(const float4*)(aE + 3 * 8192 + kcs * 32);
    float4 c3b = *(const float4*)(aE + 3 * 8192 + kcs * 32 + 4);
    __builtin_amdgcn_sched_barrier(0);

    for (int kc = 0; kc < 16; ++kc) {
        const int cur = kc & 1, nxt = cur ^ 1;
        // publish Bs[cur]: drain the 8 asyncs (oldest); keep 8 A loads in flight
        asm volatile("s_waitcnt vmcnt(8)" ::: "memory");
        __builtin_amdgcn_s_barrier();
        __builtin_amdgcn_sched_barrier(0);
        // pack current A (its loads retire here via compiler wait; 1 iter old)
        bf16x8 fa[4];
        fa[0] = pack8(c0a, c0b); fa[1] = pack8(c1a, c1b);
        fa[2] = pack8(c2a, c2b); fa[3] = pack8(c3a, c3b);
        __builtin_amdgcn_sched_barrier(0);
        const int kn = (kcs + 1) & 15;
        if (kc < 15) {
            // issue 8 asyncs for next chunk FIRST (must be oldest at next drain)
            const short* bsrc = Bp + (size_t)kn * 16384;
#pragma unroll
            for (int i = 0; i < 8; ++i) {
                int off = (i * 4 + wave) * 512;
                async16(bsrc + off + lane * 8, &Bs[nxt][off]);
            }
        }
        __builtin_amdgcn_sched_barrier(0);
        if (kc < 15) {
            // then A loads for next chunk (stay in flight across next barrier)
            c0a = *(const float4*)(aE + 0 * 8192 + kn * 32);
            c0b = *(const float4*)(aE + 0 * 8192 + kn * 32 + 4);
            c1a = *(const float4*)(aE + 1 * 8192 + kn * 32);
            c1b = *(const float4*)(aE + 1 * 8192 + kn * 32 + 4);
            c2a = *(const float4*)(aE + 2 * 8192 + kn * 32);
            c2b = *(const float4*)(aE + 2 * 8192 + kn * 32 + 4);
            c3a = *(const float4*)(aE + 3 * 8192 + kn * 32);
            c3b = *(const float4*)(aE + 3 * 8192 + kn * 32 + 4);
        }
        __builtin_amdgcn_sched_barrier(0);
        // compute: 32 MFMAs on Bs[cur]
#pragma unroll
        for (int c = 0; c < 8; ++c) {
            bf16x8 fb = *(bf16x8*)&Bs[cur][(wave * 8 + c) * 512 + lane * 8];
#pragma unroll
            for (int r = 0; r < 4; ++r)
                acc[r][c] = __builtin_amdgcn_mfma_f32_16x16x32_bf16(fa[r], fb, acc[r][c], 0, 0, 0);
        }
        kcs = kn;
    }

    // ---- epilogue a: score = sum_col tanh(acc + dproj[col]) * Wv[col] ----
    // acc[r][c][g] = enc_proj[row0 + r*16 + quad*4 + g][wave*128 + c*16 + l15]
    float part[4][4];
#pragma unroll
    for (int r = 0; r < 4; ++r)
#pragma unroll
        for (int g = 0; g < 4; ++g) part[r][g] = 0.f;
    const float* dp = dproj + (size_t)b * HID;
#pragma unroll
    for (int c = 0; c < 8; ++c) {
        int col = wave * 128 + c * 16 + l15;
        float dv = dp[col];
        float wv = Wv[col];
#pragma unroll
        for (int r = 0; r < 4; ++r)
#pragma unroll
            for (int g = 0; g < 4; ++g)
                part[r][g] += fast_tanh(acc[r][c][g] + dv) * wv;
    }
    // reduce across the 16 col-lanes (bits 0..3 of lane)
#pragma unroll
    for (int r = 0; r < 4; ++r)
#pragma unroll
        for (int g = 0; g < 4; ++g) {
            float v = part[r][g];
            v += __shfl_xor(v, 1); v += __shfl_xor(v, 2);
            v += __shfl_xor(v, 4); v += __shfl_xor(v, 8);
            part[r][g] = v;
        }
    if (l15 == 0) {
#pragma unroll
        for (int r = 0; r < 4; ++r)
#pragma unroll
            for (int g = 0; g < 4; ++g)
                fbuf[wave * 64 + r * 16 + quad * 4 + g] = part[r][g];
    }
    __syncthreads();
    if (tid < 64) {
        float s  = fbuf[tid] + fbuf[64 + tid] + fbuf[128 + tid] + fbuf[192 + tid];
        float pv = __expf(s);           // unnormalized; b_v cancels in softmax
        pbuf[tid] = pv;
        out[(size_t)NB * HID + row0 + tid] = pv;   // weights region, normalized later
        float t2 = pv;
        t2 += __shfl_xor(t2, 1);  t2 += __shfl_xor(t2, 2);  t2 += __shfl_xor(t2, 4);
        t2 += __shfl_xor(t2, 8);  t2 += __shfl_xor(t2, 16); t2 += __shfl_xor(t2, 32);
        if (tid == 0) atomicAdd(&sumacc[b], t2);
    }
    __syncthreads();

    // ---- epilogue b: partial context = sum_rows pv * E[row,:] (L2-hot re-read) ----
    const int hq = tid & 127, rh = tid >> 7;       // h = hq*4, rows rh*32..rh*32+31
    const float4* E4 = (const float4*)E;
    size_t cbase = (size_t)(row0 + rh * 32) * (HID / 4) + hq;
    float4 ca = {0.f, 0.f, 0.f, 0.f};
#pragma unroll 4
    for (int rr = 0; rr < 32; ++rr) {
        float w  = pbuf[rh * 32 + rr];
        float4 e = E4[cbase + (size_t)rr * (HID / 4)];
        ca.x += w * e.x; ca.y += w * e.y; ca.z += w * e.z; ca.w += w * e.w;
    }
    if (rh == 1) {
        fbuf[hq] = ca.x; fbuf[128 + hq] = ca.y; fbuf[256 + hq] = ca.z; fbuf[384 + hq] = ca.w;
    }
    __syncthreads();
    if (rh == 0) {
        ca.x += fbuf[hq]; ca.y += fbuf[128 + hq]; ca.z += fbuf[256 + hq]; ca.w += fbuf[384 + hq];
        float* cg = out + (size_t)b * HID + hq * 4;   // context region of d_out
        atomicAdd(cg + 0, ca.x); atomicAdd(cg + 1, ca.y);
        atomicAdd(cg + 2, ca.z); atomicAdd(cg + 3, ca.w);
    }
}

// ---------------------------------------------------------------------------
// K_finish: normalize in place, full-grid. 147456 floats / 256 = 576 blocks.
// ---------------------------------------------------------------------------
__global__ void k_finish(float* __restrict__ out, const float* __restrict__ sumacc) {
    int idx = blockIdx.x * 256 + threadIdx.x;
    if (idx < NB * HID) {
        out[idx] *= 1.0f / sumacc[idx >> 9];           // context: b = idx/HID
    } else {
        int w = idx - NB * HID;
        out[idx] *= 1.0f / sumacc[w >> 12];            // weights: b = w/SEQL
    }
}

extern "C" void kernel_launch(void* const* d_in, const int* in_sizes, int n_in,
                              void* d_out, int out_size, void* d_ws, size_t ws_size,
                              hipStream_t stream) {
    const float* E   = (const float*)d_in[0];
    const float* dec = (const float*)d_in[1];
    const float* We  = (const float*)d_in[2];
    const float* be  = (const float*)d_in[3];
    const float* Wd  = (const float*)d_in[4];
    const float* bd  = (const float*)d_in[5];
    const float* Wv  = (const float*)d_in[6];
    // d_in[7] = b_v: uniform shift per score -> cancels in softmax
    float* out = (float*)d_out;
    char*  ws  = (char*)d_ws;
    short* Bp     = (short*)(ws + WS_BP);
    float* dproj  = (float*)(ws + WS_DPROJ);
    float* sumacc = (float*)(ws + WS_SUM);

    k_pre<<<704, 256, 0, stream>>>(We, Bp, dec, Wd, be, bd, dproj, out, sumacc);
    k_main<<<NBLK, 256, 0, stream>>>(E, Bp, dproj, Wv, out, sumacc);
    k_finish<<<576, 256, 0, stream>>>(out, sumacc);
}

// Round 10
// 460.572 us; speedup vs baseline: 1.1813x; 1.1286x over previous
//
#include <hip/hip_runtime.h>
#include <hip/hip_bf16.h>

typedef __attribute__((ext_vector_type(8))) short bf16x8;
typedef __attribute__((ext_vector_type(4))) float f32x4;
typedef __attribute__((ext_vector_type(4))) short s16x4;

#define HID 512
#define NB 32
#define SEQL 4096
#define BM 64
#define NBLK 2048       // 131072 rows / 64

// workspace layout (bytes)
#define WS_BP    0              // packed bf16 W_enc: 512 KB
#define WS_DPROJ (512*1024)     // fp32 32x512: 64 KB
#define WS_SUM   (576*1024)     // fp32 32: 128 B

__device__ __forceinline__ short f2bf(float f) {
    unsigned u = __float_as_uint(f);
    unsigned r = (u + 0x7fffu + ((u >> 16) & 1u)) >> 16;   // RNE
    return (short)r;
}

__device__ __forceinline__ float fast_tanh(float x) {
    float e = __expf(2.0f * x);
    float r = __builtin_amdgcn_rcpf(e + 1.0f);
    return 1.0f - 2.0f * r;
}

// HW packed f32->bf16 RNE (no builtin on gfx950 — inline asm)
__device__ __forceinline__ unsigned cvtpk(float lo, float hi) {
    unsigned r;
    asm("v_cvt_pk_bf16_f32 %0, %1, %2" : "=v"(r) : "v"(lo), "v"(hi));
    return r;
}

// ---------------------------------------------------------------------------
// K_pre (unchanged, R3/R7 measured): (a) W_enc pack fp32->bf16 B-frag layout
// [blk 0..127], (b) dproj GEMV 8-way h-parallel [blk 128..639],
// (c) zero ctx + sumacc [blk 640..703]
// ---------------------------------------------------------------------------
__global__ void k_pre(const float* __restrict__ We, short* __restrict__ Bp,
                      const float* __restrict__ dec, const float* __restrict__ Wd,
                      const float* __restrict__ be, const float* __restrict__ bd,
                      float* __restrict__ dproj, float* __restrict__ out,
                      float* __restrict__ sumacc) {
    const int blk = blockIdx.x, t = threadIdx.x;
    if (blk < 128) {
        // Bp[kc32][nt][lane][j] = We[kc32*32 + (lane>>4)*8 + j][nt*16 + (lane&15)]
        int tid  = blk * 256 + t;
        int lane = tid & 63;
        int nt   = (tid >> 6) & 31;
        int kc   = tid >> 11;
        int k0   = kc * 32 + (lane >> 4) * 8;
        int n    = nt * 16 + (lane & 15);
        bf16x8 v;
#pragma unroll
        for (int j = 0; j < 8; ++j) v[j] = f2bf(We[(size_t)(k0 + j) * HID + n]);
        *(bf16x8*)&Bp[(size_t)tid * 8] = v;
    } else if (blk < 640) {
        __shared__ float red[8][33];
        int bid2 = blk - 128;
        int b  = bid2 >> 4, kg = bid2 & 15;     // 32 batches x 16 k-groups
        int kl = t & 31,    hc = t >> 5;        // 32 k-cols x 8 h-chunks
        int k  = kg * 32 + kl;
        const float* dr = dec + (size_t)b * HID;
        float a = 0.f;
#pragma unroll 8
        for (int j = 0; j < 64; ++j) {
            int h = hc * 64 + j;
            a += dr[h] * Wd[(size_t)h * HID + k];
        }
        red[hc][kl] = a;
        __syncthreads();
        if (hc == 0) {
            float s = be[k] + bd[k];
#pragma unroll
            for (int c = 0; c < 8; ++c) s += red[c][kl];
            dproj[(size_t)b * HID + k] = s;
        }
    } else {
        int bz = blk - 640;
        out[bz * 256 + t] = 0.f;                // zero context region (16384 f32)
        if (bz == 0 && t < NB) sumacc[t] = 0.f;
    }
}

// ---------------------------------------------------------------------------
// K_main R12: stream-once A-resident kernel.
// Post-mortem of R8-R11: every variant reads E column-chunk-wise (128-256 B
// slivers of 64 rows 2 KB apart per iter) and ALL pin at ~1.0-1.3 TB/s HBM
// (FETCH 250 MB / 205 us = 1.22 TB/s) — DRAM page-locality bound, invariant
// to occupancy (R10: 43% occ, still slow) and pipelining (R11).
// Fix: HID=512 -> the whole 64x512 A-tile is 64 KB bf16. Stage it ONCE with
// perfectly LINEAR reads (wave w sweeps a contiguous 32 KB span; 64 lanes x
// 16 B = 1 KB/instr), one __syncthreads, then a BARRIER-FREE K-loop: fa from
// LDS (row pad +8 shorts -> 2-way = free), fb fragment-ordered from L2
// (R9-proven addressing) with 1-deep register prefetch, fb[2][8] indices
// static via full unroll (rule #20). Per-block K-chunk stagger spreads L2.
// ---------------------------------------------------------------------------
__global__ __launch_bounds__(256, 2)
void k_main(const float* __restrict__ E, const short* __restrict__ Bp,
            const float* __restrict__ dproj, const float* __restrict__ Wv,
            float* __restrict__ out, float* __restrict__ sumacc) {
    __shared__ short As[BM][520];        // 64 x 520 shorts = 66.6 KB (1040 B rows)
    __shared__ float fbuf[640];
    __shared__ float pbuf[BM];

    const int tid  = threadIdx.x;
    const int wave = tid >> 6, lane = tid & 63;
    const int quad = lane >> 4, l15 = lane & 15;
    const int bid  = blockIdx.x;
    const int row0 = bid * BM;           // global row = b*4096 + s
    const int b    = bid >> 6;           // 64 blocks per batch
    const int stag = bid & 15;           // K-chunk stagger

    // ---- stage full A-tile, linear streaming: wave w -> rows 16w..16w+15 ----
    {
        const float4* src4 = (const float4*)(E + (size_t)(row0 + wave * 16) * HID);
#pragma unroll
        for (int i = 0; i < 32; ++i) {
            float4 v = src4[i * 64 + lane];          // 1 KB contiguous per instr
            int fo  = i * 256 + lane * 4;            // float offset in 16-row span
            int r16 = fo >> 9;                       // 0..15
            int col = fo & 511;
            union { unsigned u[2]; s16x4 s; } t;
            t.u[0] = cvtpk(v.x, v.y);
            t.u[1] = cvtpk(v.z, v.w);
            *(s16x4*)&As[wave * 16 + r16][col] = t.s;
        }
    }
    __syncthreads();                                  // the ONLY K-path barrier

    f32x4 acc[4][8];
#pragma unroll
    for (int r = 0; r < 4; ++r)
#pragma unroll
        for (int c = 0; c < 8; ++c) acc[r][c] = (f32x4){0.f, 0.f, 0.f, 0.f};

    // B fragment base: Bp[kc][nt = wave*8 + c][lane][8 shorts]
    const short* bpw = Bp + ((size_t)(wave * 8) * 64 + lane) * 8;

#define LOADB(dst, kk) do {                                            \
        const short* bsrc_ = bpw + (size_t)(kk) * 16384;               \
        _Pragma("unroll")                                              \
        for (int c_ = 0; c_ < 8; ++c_)                                 \
            dst[c_] = *(const bf16x8*)(bsrc_ + c_ * 512);              \
    } while (0)

    bf16x8 fb[2][8];
    LOADB(fb[0], stag);
#pragma unroll
    for (int kc = 0; kc < 16; ++kc) {
        const int cur = kc & 1, nxt = cur ^ 1;       // compile-time after unroll
        const int kcs = (stag + kc) & 15;
        if (kc < 15) LOADB(fb[nxt], (kcs + 1) & 15); // prefetch next B frags
        bf16x8 fa[4];
#pragma unroll
        for (int r = 0; r < 4; ++r)
            fa[r] = *(bf16x8*)&As[r * 16 + l15][kcs * 32 + quad * 8];
#pragma unroll
        for (int c = 0; c < 8; ++c)
#pragma unroll
            for (int r = 0; r < 4; ++r)
                acc[r][c] = __builtin_amdgcn_mfma_f32_16x16x32_bf16(fa[r], fb[cur][c], acc[r][c], 0, 0, 0);
    }
#undef LOADB

    // ---- epilogue a: score = sum_col tanh(acc + dproj[col]) * Wv[col] ----
    // acc[r][c][g] = enc_proj[row0 + r*16 + quad*4 + g][wave*128 + c*16 + l15]
    float part[4][4];
#pragma unroll
    for (int r = 0; r < 4; ++r)
#pragma unroll
        for (int g = 0; g < 4; ++g) part[r][g] = 0.f;
    const float* dp = dproj + (size_t)b * HID;
#pragma unroll
    for (int c = 0; c < 8; ++c) {
        int col = wave * 128 + c * 16 + l15;
        float dv = dp[col];
        float wv = Wv[col];
#pragma unroll
        for (int r = 0; r < 4; ++r)
#pragma unroll
            for (int g = 0; g < 4; ++g)
                part[r][g] += fast_tanh(acc[r][c][g] + dv) * wv;
    }
    // reduce across the 16 col-lanes (bits 0..3 of lane)
#pragma unroll
    for (int r = 0; r < 4; ++r)
#pragma unroll
        for (int g = 0; g < 4; ++g) {
            float v = part[r][g];
            v += __shfl_xor(v, 1); v += __shfl_xor(v, 2);
            v += __shfl_xor(v, 4); v += __shfl_xor(v, 8);
            part[r][g] = v;
        }
    if (l15 == 0) {
#pragma unroll
        for (int r = 0; r < 4; ++r)
#pragma unroll
            for (int g = 0; g < 4; ++g)
                fbuf[wave * 64 + r * 16 + quad * 4 + g] = part[r][g];
    }
    __syncthreads();
    if (tid < 64) {
        float s  = fbuf[tid] + fbuf[64 + tid] + fbuf[128 + tid] + fbuf[192 + tid];
        float pv = __expf(s);           // unnormalized; b_v cancels in softmax
        pbuf[tid] = pv;
        out[(size_t)NB * HID + row0 + tid] = pv;   // weights region, normalized later
        float t2 = pv;
        t2 += __shfl_xor(t2, 1);  t2 += __shfl_xor(t2, 2);  t2 += __shfl_xor(t2, 4);
        t2 += __shfl_xor(t2, 8);  t2 += __shfl_xor(t2, 16); t2 += __shfl_xor(t2, 32);
        if (tid == 0) atomicAdd(&sumacc[b], t2);
    }
    __syncthreads();

    // ---- epilogue b: partial context = sum_rows pv * E[row,:] (L2/L3-hot) ----
    const int hq = tid & 127, rh = tid >> 7;       // h = hq*4, rows rh*32..rh*32+31
    const float4* E4 = (const float4*)E;
    size_t cbase = (size_t)(row0 + rh * 32) * (HID / 4) + hq;
    float4 ca = {0.f, 0.f, 0.f, 0.f};
#pragma unroll 4
    for (int rr = 0; rr < 32; ++rr) {
        float w  = pbuf[rh * 32 + rr];
        float4 e = E4[cbase + (size_t)rr * (HID / 4)];
        ca.x += w * e.x; ca.y += w * e.y; ca.z += w * e.z; ca.w += w * e.w;
    }
    if (rh == 1) {
        fbuf[hq] = ca.x; fbuf[128 + hq] = ca.y; fbuf[256 + hq] = ca.z; fbuf[384 + hq] = ca.w;
    }
    __syncthreads();
    if (rh == 0) {
        ca.x += fbuf[hq]; ca.y += fbuf[128 + hq]; ca.z += fbuf[256 + hq]; ca.w += fbuf[384 + hq];
        float* cg = out + (size_t)b * HID + hq * 4;   // context region of d_out
        atomicAdd(cg + 0, ca.x); atomicAdd(cg + 1, ca.y);
        atomicAdd(cg + 2, ca.z); atomicAdd(cg + 3, ca.w);
    }
}

// ---------------------------------------------------------------------------
// K_finish: normalize in place, full-grid. 147456 floats / 256 = 576 blocks.
// ---------------------------------------------------------------------------
__global__ void k_finish(float* __restrict__ out, const float* __restrict__ sumacc) {
    int idx = blockIdx.x * 256 + threadIdx.x;
    if (idx < NB * HID) {
        out[idx] *= 1.0f / sumacc[idx >> 9];           // context: b = idx/HID
    } else {
        int w = idx - NB * HID;
        out[idx] *= 1.0f / sumacc[w >> 12];            // weights: b = w/SEQL
    }
}

extern "C" void kernel_launch(void* const* d_in, const int* in_sizes, int n_in,
                              void* d_out, int out_size, void* d_ws, size_t ws_size,
                              hipStream_t stream) {
    const float* E   = (const float*)d_in[0];
    const float* dec = (const float*)d_in[1];
    const float* We  = (const float*)d_in[2];
    const float* be  = (const float*)d_in[3];
    const float* Wd  = (const float*)d_in[4];
    const float* bd  = (const float*)d_in[5];
    const float* Wv  = (const float*)d_in[6];
    // d_in[7] = b_v: uniform shift per score -> cancels in softmax
    float* out = (float*)d_out;
    char*  ws  = (char*)d_ws;
    short* Bp     = (short*)(ws + WS_BP);
    float* dproj  = (float*)(ws + WS_DPROJ);
    float* sumacc = (float*)(ws + WS_SUM);

    k_pre<<<704, 256, 0, stream>>>(We, Bp, dec, Wd, be, bd, dproj, out, sumacc);
    k_main<<<NBLK, 256, 0, stream>>>(E, Bp, dproj, Wv, out, sumacc);
    k_finish<<<576, 256, 0, stream>>>(out, sumacc);
}

// Round 14
// 446.526 us; speedup vs baseline: 1.2185x; 1.0315x over previous
//
#include <hip/hip_runtime.h>
#include <hip/hip_bf16.h>

typedef __attribute__((ext_vector_type(8))) short bf16x8;
typedef __attribute__((ext_vector_type(4))) float f32x4;
typedef __attribute__((ext_vector_type(4))) short s16x4;

#define HID 512
#define NB 32
#define SEQL 4096
#define BM 64
#define NBLK 2048       // 131072 rows / 64

// workspace layout (bytes)
#define WS_BP    0              // packed bf16 W_enc: 512 KB
#define WS_DPROJ (512*1024)     // fp32 32x512: 64 KB
#define WS_SUM   (576*1024)     // fp32 32: 128 B

__device__ __forceinline__ short f2bf(float f) {
    unsigned u = __float_as_uint(f);
    unsigned r = (u + 0x7fffu + ((u >> 16) & 1u)) >> 16;   // RNE
    return (short)r;
}

__device__ __forceinline__ float fast_tanh(float x) {
    float e = __expf(2.0f * x);
    float r = __builtin_amdgcn_rcpf(e + 1.0f);
    return 1.0f - 2.0f * r;
}

// HW packed f32->bf16 RNE (no builtin on gfx950 — inline asm)
__device__ __forceinline__ unsigned cvtpk(float lo, float hi) {
    unsigned r;
    asm("v_cvt_pk_bf16_f32 %0, %1, %2" : "=v"(r) : "v"(lo), "v"(hi));
    return r;
}

// ---------------------------------------------------------------------------
// K_pre (unchanged, R3/R7 measured): (a) W_enc pack fp32->bf16 B-frag layout
// [blk 0..127], (b) dproj GEMV 8-way h-parallel [blk 128..639],
// (c) zero ctx + sumacc [blk 640..703]
// ---------------------------------------------------------------------------
__global__ void k_pre(const float* __restrict__ We, short* __restrict__ Bp,
                      const float* __restrict__ dec, const float* __restrict__ Wd,
                      const float* __restrict__ be, const float* __restrict__ bd,
                      float* __restrict__ dproj, float* __restrict__ out,
                      float* __restrict__ sumacc) {
    const int blk = blockIdx.x, t = threadIdx.x;
    if (blk < 128) {
        // Bp[kc32][nt][lane][j] = We[kc32*32 + (lane>>4)*8 + j][nt*16 + (lane&15)]
        int tid  = blk * 256 + t;
        int lane = tid & 63;
        int nt   = (tid >> 6) & 31;
        int kc   = tid >> 11;
        int k0   = kc * 32 + (lane >> 4) * 8;
        int n    = nt * 16 + (lane & 15);
        bf16x8 v;
#pragma unroll
        for (int j = 0; j < 8; ++j) v[j] = f2bf(We[(size_t)(k0 + j) * HID + n]);
        *(bf16x8*)&Bp[(size_t)tid * 8] = v;
    } else if (blk < 640) {
        __shared__ float red[8][33];
        int bid2 = blk - 128;
        int b  = bid2 >> 4, kg = bid2 & 15;     // 32 batches x 16 k-groups
        int kl = t & 31,    hc = t >> 5;        // 32 k-cols x 8 h-chunks
        int k  = kg * 32 + kl;
        const float* dr = dec + (size_t)b * HID;
        float a = 0.f;
#pragma unroll 8
        for (int j = 0; j < 64; ++j) {
            int h = hc * 64 + j;
            a += dr[h] * Wd[(size_t)h * HID + k];
        }
        red[hc][kl] = a;
        __syncthreads();
        if (hc == 0) {
            float s = be[k] + bd[k];
#pragma unroll
            for (int c = 0; c < 8; ++c) s += red[c][kl];
            dproj[(size_t)b * HID + k] = s;
        }
    } else {
        int bz = blk - 640;
        out[bz * 256 + t] = 0.f;                // zero context region (16384 f32)
        if (bz == 0 && t < NB) sumacc[t] = 0.f;
    }
}

// ---------------------------------------------------------------------------
// K_main R13: R12 structure (A-resident LDS, stream-once linear staging,
// barrier-free K-loop, fb fragment-ordered from L2 with stagger) at
// 512 THREADS / 8 WAVES. R12 post-mortem: MfmaUtil=VALUBusy=14.5%, occ 22%
// (2 waves/SIMD) -> phases serial; per-CU serial sum 155us ~= measured 193.
// Doubling waves/SIMD (2->4) at identical LDS/tile lets block A's staging
// overlap block B's K-loop. Wave tile 64x128 -> 64x64: acc[4][4] = 64 VGPR,
// fb[2][4] -> fits launch_bounds(512,4) <=128 VGPR (2 blocks/CU preserved).
// Total per-CU MFMA/L2/HBM work unchanged — this is pure overlap.
// ---------------------------------------------------------------------------
__global__ __launch_bounds__(512, 4)
void k_main(const float* __restrict__ E, const short* __restrict__ Bp,
            const float* __restrict__ dproj, const float* __restrict__ Wv,
            float* __restrict__ out, float* __restrict__ sumacc) {
    __shared__ short As[BM][520];        // 64 x 520 shorts = 66.6 KB (1040 B rows)
    __shared__ float fbuf[1024];
    __shared__ float pbuf[BM];

    const int tid  = threadIdx.x;
    const int wave = tid >> 6, lane = tid & 63;
    const int quad = lane >> 4, l15 = lane & 15;
    const int bid  = blockIdx.x;
    const int row0 = bid * BM;           // global row = b*4096 + s
    const int b    = bid >> 6;           // 64 blocks per batch
    const int stag = bid & 15;           // K-chunk stagger

    // ---- stage full A-tile, linear streaming: wave w -> rows 8w..8w+7 ----
    {
        const float4* src4 = (const float4*)(E + (size_t)(row0 + wave * 8) * HID);
#pragma unroll
        for (int i = 0; i < 16; ++i) {
            float4 v = src4[i * 64 + lane];          // 1 KB contiguous per instr
            int fo  = i * 256 + lane * 4;            // float offset in 8-row span
            int r8  = fo >> 9;                       // 0..7
            int col = fo & 511;
            union { unsigned u[2]; s16x4 s; } t;
            t.u[0] = cvtpk(v.x, v.y);
            t.u[1] = cvtpk(v.z, v.w);
            *(s16x4*)&As[wave * 8 + r8][col] = t.s;
        }
    }
    __syncthreads();                                  // the ONLY K-path barrier

    f32x4 acc[4][4];
#pragma unroll
    for (int r = 0; r < 4; ++r)
#pragma unroll
        for (int c = 0; c < 4; ++c) acc[r][c] = (f32x4){0.f, 0.f, 0.f, 0.f};

    // B fragment base: Bp[kc][nt = wave*4 + c][lane][8 shorts]
    const short* bpw = Bp + ((size_t)(wave * 4) * 64 + lane) * 8;

#define LOADB(dst, kk) do {                                            \
        const short* bsrc_ = bpw + (size_t)(kk) * 16384;               \
        _Pragma("unroll")                                              \
        for (int c_ = 0; c_ < 4; ++c_)                                 \
            dst[c_] = *(const bf16x8*)(bsrc_ + c_ * 512);              \
    } while (0)

    bf16x8 fb[2][4];
    LOADB(fb[0], stag);
#pragma unroll
    for (int kc = 0; kc < 16; ++kc) {
        const int cur = kc & 1, nxt = cur ^ 1;       // compile-time after unroll
        const int kcs = (stag + kc) & 15;
        if (kc < 15) LOADB(fb[nxt], (kcs + 1) & 15); // prefetch next B frags
        bf16x8 fa[4];
#pragma unroll
        for (int r = 0; r < 4; ++r)
            fa[r] = *(bf16x8*)&As[r * 16 + l15][kcs * 32 + quad * 8];
#pragma unroll
        for (int c = 0; c < 4; ++c)
#pragma unroll
            for (int r = 0; r < 4; ++r)
                acc[r][c] = __builtin_amdgcn_mfma_f32_16x16x32_bf16(fa[r], fb[cur][c], acc[r][c], 0, 0, 0);
    }
#undef LOADB

    // ---- epilogue a: score = sum_col tanh(acc + dproj[col]) * Wv[col] ----
    // acc[r][c][g] = enc_proj[row0 + r*16 + quad*4 + g][wave*64 + c*16 + l15]
    float part[4][4];
#pragma unroll
    for (int r = 0; r < 4; ++r)
#pragma unroll
        for (int g = 0; g < 4; ++g) part[r][g] = 0.f;
    const float* dp = dproj + (size_t)b * HID;
#pragma unroll
    for (int c = 0; c < 4; ++c) {
        int col = wave * 64 + c * 16 + l15;
        float dv = dp[col];
        float wv = Wv[col];
#pragma unroll
        for (int r = 0; r < 4; ++r)
#pragma unroll
            for (int g = 0; g < 4; ++g)
                part[r][g] += fast_tanh(acc[r][c][g] + dv) * wv;
    }
    // reduce across the 16 col-lanes (bits 0..3 of lane)
#pragma unroll
    for (int r = 0; r < 4; ++r)
#pragma unroll
        for (int g = 0; g < 4; ++g) {
            float v = part[r][g];
            v += __shfl_xor(v, 1); v += __shfl_xor(v, 2);
            v += __shfl_xor(v, 4); v += __shfl_xor(v, 8);
            part[r][g] = v;
        }
    if (l15 == 0) {
#pragma unroll
        for (int r = 0; r < 4; ++r)
#pragma unroll
            for (int g = 0; g < 4; ++g)
                fbuf[wave * 64 + r * 16 + quad * 4 + g] = part[r][g];
    }
    __syncthreads();
    if (tid < 64) {
        float s = fbuf[tid];
#pragma unroll
        for (int w = 1; w < 8; ++w) s += fbuf[w * 64 + tid];
        float pv = __expf(s);           // unnormalized; b_v cancels in softmax
        pbuf[tid] = pv;
        out[(size_t)NB * HID + row0 + tid] = pv;   // weights region, normalized later
        float t2 = pv;
        t2 += __shfl_xor(t2, 1);  t2 += __shfl_xor(t2, 2);  t2 += __shfl_xor(t2, 4);
        t2 += __shfl_xor(t2, 8);  t2 += __shfl_xor(t2, 16); t2 += __shfl_xor(t2, 32);
        if (tid == 0) atomicAdd(&sumacc[b], t2);
    }
    __syncthreads();

    // ---- epilogue b: partial context = sum_rows pv * E[row,:] (L2-hot) ----
    const int hq = tid & 127, rh = tid >> 7;       // h = hq*4, rows rh*16..rh*16+15
    const float4* E4 = (const float4*)E;
    size_t cbase = (size_t)(row0 + rh * 16) * (HID / 4) + hq;
    float4 ca = {0.f, 0.f, 0.f, 0.f};
#pragma unroll 4
    for (int rr = 0; rr < 16; ++rr) {
        float w  = pbuf[rh * 16 + rr];
        float4 e = E4[cbase + (size_t)rr * (HID / 4)];
        ca.x += w * e.x; ca.y += w * e.y; ca.z += w * e.z; ca.w += w * e.w;
    }
    // 4-group reduction tree in fbuf (1024 floats)
    if (rh >= 2) {
        int base = (rh - 2) * 512;
        fbuf[base + hq] = ca.x;        fbuf[base + 128 + hq] = ca.y;
        fbuf[base + 256 + hq] = ca.z;  fbuf[base + 384 + hq] = ca.w;
    }
    __syncthreads();
    if (rh < 2) {
        int base = rh * 512;
        ca.x += fbuf[base + hq];       ca.y += fbuf[base + 128 + hq];
        ca.z += fbuf[base + 256 + hq]; ca.w += fbuf[base + 384 + hq];
        if (rh == 1) {   // write into region 512 (own source, already consumed)
            fbuf[512 + hq] = ca.x;        fbuf[512 + 128 + hq] = ca.y;
            fbuf[512 + 256 + hq] = ca.z;  fbuf[512 + 384 + hq] = ca.w;
        }
    }
    __syncthreads();
    if (rh == 0) {
        ca.x += fbuf[512 + hq];       ca.y += fbuf[512 + 128 + hq];
        ca.z += fbuf[512 + 256 + hq]; ca.w += fbuf[512 + 384 + hq];
        float* cg = out + (size_t)b * HID + hq * 4;   // context region of d_out
        atomicAdd(cg + 0, ca.x); atomicAdd(cg + 1, ca.y);
        atomicAdd(cg + 2, ca.z); atomicAdd(cg + 3, ca.w);
    }
}

// ---------------------------------------------------------------------------
// K_finish: normalize in place, full-grid. 147456 floats / 256 = 576 blocks.
// ---------------------------------------------------------------------------
__global__ void k_finish(float* __restrict__ out, const float* __restrict__ sumacc) {
    int idx = blockIdx.x * 256 + threadIdx.x;
    if (idx < NB * HID) {
        out[idx] *= 1.0f / sumacc[idx >> 9];           // context: b = idx/HID
    } else {
        int w = idx - NB * HID;
        out[idx] *= 1.0f / sumacc[w >> 12];            // weights: b = w/SEQL
    }
}

extern "C" void kernel_launch(void* const* d_in, const int* in_sizes, int n_in,
                              void* d_out, int out_size, void* d_ws, size_t ws_size,
                              hipStream_t stream) {
    const float* E   = (const float*)d_in[0];
    const float* dec = (const float*)d_in[1];
    const float* We  = (const float*)d_in[2];
    const float* be  = (const float*)d_in[3];
    const float* Wd  = (const float*)d_in[4];
    const float* bd  = (const float*)d_in[5];
    const float* Wv  = (const float*)d_in[6];
    // d_in[7] = b_v: uniform shift per score -> cancels in softmax
    float* out = (float*)d_out;
    char*  ws  = (char*)d_ws;
    short* Bp     = (short*)(ws + WS_BP);
    float* dproj  = (float*)(ws + WS_DPROJ);
    float* sumacc = (float*)(ws + WS_SUM);

    k_pre<<<704, 256, 0, stream>>>(We, Bp, dec, Wd, be, bd, dproj, out, sumacc);
    k_main<<<NBLK, 512, 0, stream>>>(E, Bp, dproj, Wv, out, sumacc);
    k_finish<<<576, 256, 0, stream>>>(out, sumacc);
}